// Round 1
// baseline (152.466 us; speedup 1.0000x reference)
//
#include <hip/hip_runtime.h>
#include <math.h>

// Chamfer one-sided NN distance sum.
// N = M = 16384, D = 3, fp32 in, scalar fp32 out.
//
// Structure:
//  k0: init  — ws_min[i] = +inf bits, out = 0   (harness re-poisons every call)
//  k1: pair  — 64 a-tiles x 32 b-slices; per-thread min d2 over a 512-pt LDS
//              slice of B; atomicMin(uint bits) into ws_min[a_idx]
//  k2: reduce— sqrt(min d2) per a-point, block-tree-sum, atomicAdd to out

#define NPTS  16384
#define BLOCK 256
#define SLICES 32
#define SLICE (NPTS / SLICES)   // 512 b-points per block

__global__ __launch_bounds__(BLOCK)
void cd_init_kernel(unsigned int* __restrict__ ws_min, float* __restrict__ out, int n) {
    int i = blockIdx.x * BLOCK + threadIdx.x;
    if (i < n) ws_min[i] = 0x7F800000u;   // +inf (float bits)
    if (i == 0) out[0] = 0.0f;
}

__global__ __launch_bounds__(BLOCK)
void cd_pair_min_kernel(const float* __restrict__ a,
                        const float* __restrict__ b,
                        unsigned int* __restrict__ ws_min,
                        int n) {
    // SoA LDS tile of B: wave-uniform inner-loop reads -> broadcast, no bank conflicts
    __shared__ float bx[SLICE], by[SLICE], bz[SLICE];
    const int slice_base = blockIdx.y * SLICE;

    for (int j = threadIdx.x; j < SLICE; j += BLOCK) {
        int gj = slice_base + j;
        bx[j] = b[3 * gj + 0];
        by[j] = b[3 * gj + 1];
        bz[j] = b[3 * gj + 2];
    }
    __syncthreads();

    const int i = blockIdx.x * BLOCK + threadIdx.x;
    if (i >= n) return;

    const float ax = a[3 * i + 0];
    const float ay = a[3 * i + 1];
    const float az = a[3 * i + 2];

    float best = 3.4028235e38f;
    #pragma unroll 8
    for (int j = 0; j < SLICE; ++j) {
        float dx = ax - bx[j];
        float dy = ay - by[j];
        float dz = az - bz[j];
        float d2 = fmaf(dz, dz, fmaf(dy, dy, dx * dx));
        best = fminf(best, d2);
    }
    // d2 >= 0 so fp32 bit pattern is monotone as uint -> atomicMin on bits
    atomicMin(ws_min + i, __float_as_uint(best));
}

__global__ __launch_bounds__(BLOCK)
void cd_reduce_kernel(const unsigned int* __restrict__ ws_min,
                      float* __restrict__ out, int n) {
    __shared__ float red[BLOCK / 64];
    const int stride = gridDim.x * BLOCK;
    float s = 0.0f;
    for (int i = blockIdx.x * BLOCK + threadIdx.x; i < n; i += stride)
        s += sqrtf(__uint_as_float(ws_min[i]));

    // wave-64 butterfly
    for (int off = 32; off > 0; off >>= 1)
        s += __shfl_down(s, off, 64);

    const int lane = threadIdx.x & 63;
    const int wave = threadIdx.x >> 6;
    if (lane == 0) red[wave] = s;
    __syncthreads();
    if (threadIdx.x == 0) {
        float t = 0.0f;
        for (int w = 0; w < BLOCK / 64; ++w) t += red[w];
        atomicAdd(out, t);
    }
}

extern "C" void kernel_launch(void* const* d_in, const int* in_sizes, int n_in,
                              void* d_out, int out_size, void* d_ws, size_t ws_size,
                              hipStream_t stream) {
    const float* a = (const float*)d_in[0];
    const float* b = (const float*)d_in[1];
    float* out = (float*)d_out;
    const int n = in_sizes[0] / 3;   // 16384
    unsigned int* ws_min = (unsigned int*)d_ws;   // n uints of partial-min d2 bits

    cd_init_kernel<<<(n + BLOCK - 1) / BLOCK, BLOCK, 0, stream>>>(ws_min, out, n);

    dim3 grid((n + BLOCK - 1) / BLOCK, SLICES);   // 64 x 32 = 2048 blocks
    cd_pair_min_kernel<<<grid, BLOCK, 0, stream>>>(a, b, ws_min, n);

    cd_reduce_kernel<<<64, BLOCK, 0, stream>>>(ws_min, out, n);
}

// Round 2
// 97.831 us; speedup vs baseline: 1.5585x; 1.5585x over previous
//
#include <hip/hip_runtime.h>
#include <math.h>

// Chamfer one-sided NN distance sum. N = M = 16384, D = 3, fp32 -> scalar fp32.
//
// k1 pair:   grid (a_tiles, slices). Each thread owns 8 a-points; each block
//            stages slice_len b-points as float4(-2bx,-2by,-2bz,|b|^2) in LDS.
//            Inner loop: 1 ds_read_b128 per j, then per a-point
//            t = fma(ax,vx, fma(ay,vy, fma(az,vz, b2))); best = min(best, t)
//            -> 4 VALU/pair, LDS reads amortized 8x. Partial mins written
//            non-atomically to ws[slice][a] (no init kernel needed).
// k2 reduce: min over slices, d2 = max(min + |a|^2, 0), sqrt, block-sum,
//            atomicAdd into out (zeroed by hipMemsetAsync — graph-safe).

#define BLOCK 256
#define APT   8                 // a-points per thread
#define SLICE_MAX 1024          // LDS float4 capacity (16 KB)

__global__ __launch_bounds__(BLOCK)
void cd_pair_kernel(const float* __restrict__ a,
                    const float* __restrict__ b,
                    float* __restrict__ ws,
                    int n, int slice_len) {
    __shared__ float4 sb[SLICE_MAX];
    const int slice = blockIdx.y;
    const int base  = slice * slice_len;

    for (int j = threadIdx.x; j < slice_len; j += BLOCK) {
        const int gj = base + j;
        const float x = b[3 * gj + 0];
        const float y = b[3 * gj + 1];
        const float z = b[3 * gj + 2];
        const float b2 = fmaf(x, x, fmaf(y, y, z * z));
        sb[j] = make_float4(-2.0f * x, -2.0f * y, -2.0f * z, b2);
    }
    __syncthreads();

    const int a_base = blockIdx.x * (BLOCK * APT);
    float ax[APT], ay[APT], az[APT], best[APT];
    #pragma unroll
    for (int k = 0; k < APT; ++k) {
        const int i = a_base + k * BLOCK + threadIdx.x;
        ax[k] = a[3 * i + 0];
        ay[k] = a[3 * i + 1];
        az[k] = a[3 * i + 2];
        best[k] = 3.4028235e38f;
    }

    #pragma unroll 2
    for (int j = 0; j < slice_len; ++j) {
        const float4 v = sb[j];   // ds_read_b128, wave-uniform broadcast
        #pragma unroll
        for (int k = 0; k < APT; ++k) {
            float t = fmaf(az[k], v.z, v.w);
            t = fmaf(ay[k], v.y, t);
            t = fmaf(ax[k], v.x, t);
            best[k] = fminf(best[k], t);
        }
    }

    #pragma unroll
    for (int k = 0; k < APT; ++k) {
        const int i = a_base + k * BLOCK + threadIdx.x;
        ws[slice * n + i] = best[k];   // coalesced, no atomics
    }
}

__global__ __launch_bounds__(BLOCK)
void cd_reduce_kernel(const float* __restrict__ a,
                      const float* __restrict__ ws,
                      float* __restrict__ out,
                      int n, int slices) {
    __shared__ float red[BLOCK / 64];
    const int i = blockIdx.x * BLOCK + threadIdx.x;   // one thread per a-point

    float m = 3.4028235e38f;
    for (int s = 0; s < slices; ++s)
        m = fminf(m, ws[s * n + i]);   // coalesced across threads

    const float x = a[3 * i + 0];
    const float y = a[3 * i + 1];
    const float z = a[3 * i + 2];
    const float a2 = fmaf(x, x, fmaf(y, y, z * z));
    float sum = sqrtf(fmaxf(m + a2, 0.0f));

    for (int off = 32; off > 0; off >>= 1)
        sum += __shfl_down(sum, off, 64);

    const int lane = threadIdx.x & 63;
    const int wave = threadIdx.x >> 6;
    if (lane == 0) red[wave] = sum;
    __syncthreads();
    if (threadIdx.x == 0) {
        float t = 0.0f;
        for (int w = 0; w < BLOCK / 64; ++w) t += red[w];
        atomicAdd(out, t);
    }
}

extern "C" void kernel_launch(void* const* d_in, const int* in_sizes, int n_in,
                              void* d_out, int out_size, void* d_ws, size_t ws_size,
                              hipStream_t stream) {
    const float* a = (const float*)d_in[0];
    const float* b = (const float*)d_in[1];
    float* out = (float*)d_out;
    const int n = in_sizes[0] / 3;    // 16384
    float* ws = (float*)d_ws;

    // Pick slice count: prefer 64 slices (slice_len=256) for occupancy;
    // need ws >= slices * n * 4 bytes and slice_len <= SLICE_MAX.
    int slices = 64;
    while (slices > 1 &&
           ((size_t)slices * (size_t)n * sizeof(float) > ws_size ||
            n / slices > SLICE_MAX))
        slices >>= 1;
    const int slice_len = n / slices;
    const int a_tiles = n / (BLOCK * APT);   // 8 for n=16384

    hipMemsetAsync(out, 0, sizeof(float), stream);

    dim3 grid(a_tiles, slices);   // 8 x 64 = 512 blocks
    cd_pair_kernel<<<grid, BLOCK, 0, stream>>>(a, b, ws, n, slice_len);

    cd_reduce_kernel<<<n / BLOCK, BLOCK, 0, stream>>>(a, ws, out, n, slices);
}

// Round 3
// 89.565 us; speedup vs baseline: 1.7023x; 1.0923x over previous
//
#include <hip/hip_runtime.h>
#include <math.h>

// Chamfer one-sided NN distance sum. N = M = 16384, D = 3, fp32 -> scalar fp32.
//
// k1 pair:   grid (a_tiles=4, slices=128) = 512 blocks. Each thread owns 16
//            a-points held as 8 float2 (encourages v_pk_fma_f32). Block stages
//            slice_len=128 b-points as float4(-2bx,-2by,-2bz,|b|^2) in LDS
//            (2 KB). Inner: 1 ds_read_b128 per j amortized over 16 a-points;
//            3 fma + 1 min per pair. Partial mins -> ws[slice][a], no atomics.
//            Block (0,0) also zeroes out[0] (replaces memset node; safe since
//            reduce launches after on the same stream).
// k2 reduce: min over slices, d2 = max(min + |a|^2, 0), sqrt, wave+block sum,
//            atomicAdd into out.

#define BLOCK 256
#define HPT   8                  // float2 pairs per thread -> 16 a-points
#define APT   (2 * HPT)

__global__ __launch_bounds__(BLOCK)
void cd_pair_kernel(const float* __restrict__ a,
                    const float* __restrict__ b,
                    float* __restrict__ ws,
                    float* __restrict__ out,
                    int n, int slice_len) {
    extern __shared__ float4 sb[];
    const int slice = blockIdx.y;
    const int base  = slice * slice_len;

    for (int j = threadIdx.x; j < slice_len; j += BLOCK) {
        const int gj = base + j;
        const float x = b[3 * gj + 0];
        const float y = b[3 * gj + 1];
        const float z = b[3 * gj + 2];
        const float b2 = fmaf(x, x, fmaf(y, y, z * z));
        sb[j] = make_float4(-2.0f * x, -2.0f * y, -2.0f * z, b2);
    }
    if (blockIdx.x == 0 && blockIdx.y == 0 && threadIdx.x == 0)
        out[0] = 0.0f;   // replaces a separate memset node
    __syncthreads();

    const int a_base = blockIdx.x * (BLOCK * APT);
    float2 ax[HPT], ay[HPT], az[HPT], best[HPT];
    #pragma unroll
    for (int h = 0; h < HPT; ++h) {
        const int i0 = a_base + (2 * h + 0) * BLOCK + threadIdx.x;
        const int i1 = a_base + (2 * h + 1) * BLOCK + threadIdx.x;
        ax[h] = make_float2(a[3 * i0 + 0], a[3 * i1 + 0]);
        ay[h] = make_float2(a[3 * i0 + 1], a[3 * i1 + 1]);
        az[h] = make_float2(a[3 * i0 + 2], a[3 * i1 + 2]);
        best[h] = make_float2(3.4028235e38f, 3.4028235e38f);
    }

    #pragma unroll 2
    for (int j = 0; j < slice_len; ++j) {
        const float4 v = sb[j];   // wave-uniform broadcast, no conflicts
        #pragma unroll
        for (int h = 0; h < HPT; ++h) {
            float2 t;
            t.x = fmaf(az[h].x, v.z, v.w);
            t.y = fmaf(az[h].y, v.z, v.w);
            t.x = fmaf(ay[h].x, v.y, t.x);
            t.y = fmaf(ay[h].y, v.y, t.y);
            t.x = fmaf(ax[h].x, v.x, t.x);
            t.y = fmaf(ax[h].y, v.x, t.y);
            best[h].x = fminf(best[h].x, t.x);
            best[h].y = fminf(best[h].y, t.y);
        }
    }

    float* wrow = ws + (size_t)slice * n;
    #pragma unroll
    for (int h = 0; h < HPT; ++h) {
        wrow[a_base + (2 * h + 0) * BLOCK + threadIdx.x] = best[h].x;
        wrow[a_base + (2 * h + 1) * BLOCK + threadIdx.x] = best[h].y;
    }
}

__global__ __launch_bounds__(BLOCK)
void cd_reduce_kernel(const float* __restrict__ a,
                      const float* __restrict__ ws,
                      float* __restrict__ out,
                      int n, int slices) {
    __shared__ float red[BLOCK / 64];
    const int i = blockIdx.x * BLOCK + threadIdx.x;   // one thread per a-point

    float m = 3.4028235e38f;
    #pragma unroll 4
    for (int s = 0; s < slices; ++s)
        m = fminf(m, ws[(size_t)s * n + i]);   // coalesced across threads

    const float x = a[3 * i + 0];
    const float y = a[3 * i + 1];
    const float z = a[3 * i + 2];
    const float a2 = fmaf(x, x, fmaf(y, y, z * z));
    float sum = sqrtf(fmaxf(m + a2, 0.0f));

    for (int off = 32; off > 0; off >>= 1)
        sum += __shfl_down(sum, off, 64);

    const int lane = threadIdx.x & 63;
    const int wave = threadIdx.x >> 6;
    if (lane == 0) red[wave] = sum;
    __syncthreads();
    if (threadIdx.x == 0) {
        float t = 0.0f;
        for (int w = 0; w < BLOCK / 64; ++w) t += red[w];
        atomicAdd(out, t);
    }
}

extern "C" void kernel_launch(void* const* d_in, const int* in_sizes, int n_in,
                              void* d_out, int out_size, void* d_ws, size_t ws_size,
                              hipStream_t stream) {
    const float* a = (const float*)d_in[0];
    const float* b = (const float*)d_in[1];
    float* out = (float*)d_out;
    const int n = in_sizes[0] / 3;    // 16384
    float* ws = (float*)d_ws;

    // slices=128 -> slice_len=128, ws = 8 MB; halve if ws too small.
    int slices = 128;
    while (slices > 1 &&
           (size_t)slices * (size_t)n * sizeof(float) > ws_size)
        slices >>= 1;
    const int slice_len = n / slices;
    const int a_tiles = n / (BLOCK * APT);   // 4 for n=16384

    dim3 grid(a_tiles, slices);   // 4 x 128 = 512 blocks
    cd_pair_kernel<<<grid, BLOCK, slice_len * sizeof(float4), stream>>>(
        a, b, ws, out, n, slice_len);

    cd_reduce_kernel<<<n / BLOCK, BLOCK, 0, stream>>>(a, ws, out, n, slices);
}